// Round 1
// baseline (857.984 us; speedup 1.0000x reference)
//
#include <hip/hip_runtime.h>

#define NROUTES 1152
#define NCAPS   10
#define INCH    8
#define OUTCH   16
#define NBATCH  512
#define NITER   3
#define TPB     384   // 6 waves
#define RPT     3     // routes per thread: 384*3 = 1152
#define NB      2     // batches per workgroup
#define NWAVES  (TPB / 64)

__global__ __launch_bounds__(TPB, 2)
void caps_route_kernel(const float* __restrict__ X,     // (R, B, I)
                       const float* __restrict__ W,     // (R, C, O, I)
                       float* __restrict__ OUT)         // (B, C, O)
{
    const int t    = threadIdx.x;
    const int wid  = t >> 6;
    const int lane = t & 63;
    const int c    = blockIdx.x / (NBATCH / NB);
    const int b0   = (blockIdx.x % (NBATCH / NB)) * NB;

    __shared__ float red[NWAVES][NB][20];   // per-wave partials: [0..15]=S, [16]=Z
    __shared__ float fin[NB][20];           // reduced totals
    __shared__ float redmax[NWAVES][NB];

    float u[NB][RPT][OUTCH];   // u_hat fragments (96 VGPRs)
    float bij[NB][RPT];        // routing logits
    float vjv[NB][OUTCH];      // partial S during reduce; v after squash

    // ---------------- u_hat = W[r,c] @ x[r,b] ----------------
    #pragma unroll
    for (int j = 0; j < RPT; ++j) {
        const int r = t * RPT + j;
        const float* xp = X + ((size_t)r * NBATCH + b0) * INCH;
        float xv[NB][INCH];
        #pragma unroll
        for (int nb = 0; nb < NB; ++nb) {
            float4 a0 = *reinterpret_cast<const float4*>(xp + nb * INCH);
            float4 a1 = *reinterpret_cast<const float4*>(xp + nb * INCH + 4);
            xv[nb][0] = a0.x; xv[nb][1] = a0.y; xv[nb][2] = a0.z; xv[nb][3] = a0.w;
            xv[nb][4] = a1.x; xv[nb][5] = a1.y; xv[nb][6] = a1.z; xv[nb][7] = a1.w;
        }
        const float* wp = W + ((size_t)r * NCAPS + c) * (OUTCH * INCH);
        #pragma unroll
        for (int o = 0; o < OUTCH; ++o) {
            float4 w0 = *reinterpret_cast<const float4*>(wp + o * INCH);
            float4 w1 = *reinterpret_cast<const float4*>(wp + o * INCH + 4);
            #pragma unroll
            for (int nb = 0; nb < NB; ++nb) {
                float acc = w0.x * xv[nb][0];
                acc = fmaf(w0.y, xv[nb][1], acc);
                acc = fmaf(w0.z, xv[nb][2], acc);
                acc = fmaf(w0.w, xv[nb][3], acc);
                acc = fmaf(w1.x, xv[nb][4], acc);
                acc = fmaf(w1.y, xv[nb][5], acc);
                acc = fmaf(w1.z, xv[nb][6], acc);
                acc = fmaf(w1.w, xv[nb][7], acc);
                u[nb][j][o] = acc;
            }
        }
    }

    #pragma unroll
    for (int nb = 0; nb < NB; ++nb)
        #pragma unroll
        for (int j = 0; j < RPT; ++j)
            bij[nb][j] = 0.0f;

    // ---------------- dynamic routing ----------------
    for (int it = 0; it < NITER; ++it) {
        // ---- block max of bij (for stable softmax) ----
        float mx[NB];
        #pragma unroll
        for (int nb = 0; nb < NB; ++nb) {
            float m = bij[nb][0];
            #pragma unroll
            for (int j = 1; j < RPT; ++j) m = fmaxf(m, bij[nb][j]);
            mx[nb] = m;
        }
        #pragma unroll
        for (int sh = 1; sh <= 32; sh <<= 1) {
            #pragma unroll
            for (int nb = 0; nb < NB; ++nb)
                mx[nb] = fmaxf(mx[nb], __shfl_xor(mx[nb], sh));
        }
        if (lane == 0) {
            #pragma unroll
            for (int nb = 0; nb < NB; ++nb) redmax[wid][nb] = mx[nb];
        }
        __syncthreads();
        #pragma unroll
        for (int nb = 0; nb < NB; ++nb) {
            float m = redmax[0][nb];
            #pragma unroll
            for (int w = 1; w < NWAVES; ++w) m = fmaxf(m, redmax[w][nb]);
            mx[nb] = m;
        }

        // ---- e = exp(b - max); partial Z and S = sum e*u ----
        float Z[NB];
        #pragma unroll
        for (int nb = 0; nb < NB; ++nb) {
            Z[nb] = 0.0f;
            #pragma unroll
            for (int o = 0; o < OUTCH; ++o) vjv[nb][o] = 0.0f;
            #pragma unroll
            for (int j = 0; j < RPT; ++j) {
                float ev = __expf(bij[nb][j] - mx[nb]);
                Z[nb] += ev;
                #pragma unroll
                for (int o = 0; o < OUTCH; ++o)
                    vjv[nb][o] = fmaf(ev, u[nb][j][o], vjv[nb][o]);
            }
        }

        // ---- wave butterfly reduce of {S[16], Z} per nb ----
        #pragma unroll
        for (int sh = 1; sh <= 32; sh <<= 1) {
            #pragma unroll
            for (int nb = 0; nb < NB; ++nb) {
                Z[nb] += __shfl_xor(Z[nb], sh);
                #pragma unroll
                for (int o = 0; o < OUTCH; ++o)
                    vjv[nb][o] += __shfl_xor(vjv[nb][o], sh);
            }
        }
        if (lane == 0) {
            #pragma unroll
            for (int nb = 0; nb < NB; ++nb) {
                #pragma unroll
                for (int o = 0; o < OUTCH; ++o) red[wid][nb][o] = vjv[nb][o];
                red[wid][nb][16] = Z[nb];
            }
        }
        __syncthreads();

        // ---- cross-wave reduce: threads 0..33 each own one value ----
        if (t < NB * 17) {
            const int nb = t / 17, k = t % 17;
            float s = red[0][nb][k];
            #pragma unroll
            for (int w = 1; w < NWAVES; ++w) s += red[w][nb][k];
            fin[nb][k] = s;
        }
        __syncthreads();

        // ---- squash (every thread redundantly; values broadcast from LDS) ----
        #pragma unroll
        for (int nb = 0; nb < NB; ++nb) {
            float4 s0 = *reinterpret_cast<const float4*>(&fin[nb][0]);
            float4 s1 = *reinterpret_cast<const float4*>(&fin[nb][4]);
            float4 s2 = *reinterpret_cast<const float4*>(&fin[nb][8]);
            float4 s3 = *reinterpret_cast<const float4*>(&fin[nb][12]);
            float Zt  = fin[nb][16];
            float rZ  = 1.0f / Zt;
            float sv[OUTCH] = { s0.x, s0.y, s0.z, s0.w,
                                s1.x, s1.y, s1.z, s1.w,
                                s2.x, s2.y, s2.z, s2.w,
                                s3.x, s3.y, s3.z, s3.w };
            float n2 = 0.0f;
            #pragma unroll
            for (int o = 0; o < OUTCH; ++o) {
                sv[o] *= rZ;
                n2 = fmaf(sv[o], sv[o], n2);
            }
            float sc = sqrtf(n2) / (1.0f + n2);
            #pragma unroll
            for (int o = 0; o < OUTCH; ++o) vjv[nb][o] = sv[o] * sc;
        }

        // ---- logit update: b += <u, v>  (skip on last iter) ----
        if (it < NITER - 1) {
            #pragma unroll
            for (int nb = 0; nb < NB; ++nb)
                #pragma unroll
                for (int j = 0; j < RPT; ++j) {
                    float d = 0.0f;
                    #pragma unroll
                    for (int o = 0; o < OUTCH; ++o)
                        d = fmaf(u[nb][j][o], vjv[nb][o], d);
                    bij[nb][j] += d;
                }
        }
        __syncthreads();   // protect red/redmax/fin reuse next iteration
    }

    // ---------------- write v: out[b, c, :] ----------------
    if (t == 0) {
        #pragma unroll
        for (int nb = 0; nb < NB; ++nb) {
            float* op = OUT + ((size_t)(b0 + nb) * NCAPS + c) * OUTCH;
            #pragma unroll
            for (int o = 0; o < OUTCH; o += 4) {
                *reinterpret_cast<float4*>(op + o) =
                    make_float4(vjv[nb][o], vjv[nb][o + 1],
                                vjv[nb][o + 2], vjv[nb][o + 3]);
            }
        }
    }
}

extern "C" void kernel_launch(void* const* d_in, const int* in_sizes, int n_in,
                              void* d_out, int out_size, void* d_ws, size_t ws_size,
                              hipStream_t stream) {
    const float* X = (const float*)d_in[0];            // (1152, 512, 8)
    const float* W = (const float*)d_in[1];            // (1152, 10, 16, 8)
    float* OUT     = (float*)d_out;                    // (512, 10, 16)
    dim3 grid(NCAPS * (NBATCH / NB));                  // 2560 workgroups, c-major
    caps_route_kernel<<<grid, dim3(TPB), 0, stream>>>(X, W, OUT);
}